// Round 2
// baseline (553.842 us; speedup 1.0000x reference)
//
#include <hip/hip_runtime.h>
#include <hip/hip_bf16.h>

#define NB 4
#define CIN 128
#define NN 4096
#define DD 16
#define GG 4
#define EPSGN 1e-5f
#define SPLIT 32
#define MLEN (NN / SPLIT)     // 128 per split task

// ---------------- workspace layout (floats) ----------------
#define OFF_Q      0          // [b][n][d]   262144
#define OFF_KT     262144     // [b][m][d]
#define OFF_VT     524288     // [b][m][d]
#define OFF_VS     786432     // [b][m][d]  v * colinv
#define OFF_T      1048576    // [b][n][o]
#define OFF_RINV   1310720    // [b][n]     16384
#define OFF_RSUM   1327104    // zeroed region starts here
#define OFF_CSUM   1343488
#define OFF_XR     1359872    // [b][n][d]  262144
#define OFF_GN     1622016    // [b][g][2]  32
#define ZERO_START 1327104
#define ZERO_FLTS  294944     // 1622048 - 1327104

// K1: 1x1 convs + positional terms -> q, kT, vT.
// 256 threads = 4 waves; lane <-> n (64 per block), wave <-> 32-channel slice.
// LDS tree combine. grid = 256 blocks.
__global__ __launch_bounds__(256) void k_qkv(
    const float* __restrict__ x_q, const float* __restrict__ x_kv,
    const float* __restrict__ xyz_q, const float* __restrict__ xyz_kv,
    const float* __restrict__ w_qk, const float* __restrict__ w_v,
    const float* __restrict__ b_v, const float* __restrict__ w_pos_q,
    const float* __restrict__ w_pos_kv,
    float* __restrict__ q, float* __restrict__ kT, float* __restrict__ vT)
{
    __shared__ float part[2][64][49];
    int lane = threadIdx.x & 63;
    int w = threadIdx.x >> 6;          // 0..3
    int g0 = blockIdx.x * 64;          // global row base (b*NN+n)
    int b = g0 >> 12;
    int n = (g0 & (NN - 1)) + lane;
    const float* xq = x_q  + (size_t)b * CIN * NN + n;
    const float* xk = x_kv + (size_t)b * CIN * NN + n;

    float aq[DD], ak[DD], av[DD];
#pragma unroll
    for (int d = 0; d < DD; ++d) { aq[d] = 0.f; ak[d] = 0.f; av[d] = 0.f; }

    for (int ci = 0; ci < 32; ++ci) {
        int c = w * 32 + ci;
        float vq = xq[(size_t)c * NN];
        float vk = xk[(size_t)c * NN];
#pragma unroll
        for (int d = 0; d < DD; ++d) {
            float wq = w_qk[d * CIN + c];            // uniform -> scalar
            aq[d] = fmaf(wq, vq, aq[d]);
            ak[d] = fmaf(wq, vk, ak[d]);
            av[d] = fmaf(w_v[d * CIN + c], vk, av[d]);
        }
    }

    // tree combine: waves 2,3 -> LDS; 0,1 add; 1 -> LDS; 0 adds.
    if (w >= 2) {
#pragma unroll
        for (int d = 0; d < DD; ++d) {
            part[w - 2][lane][d]      = aq[d];
            part[w - 2][lane][d + 16] = ak[d];
            part[w - 2][lane][d + 32] = av[d];
        }
    }
    __syncthreads();
    if (w < 2) {
#pragma unroll
        for (int d = 0; d < DD; ++d) {
            aq[d] += part[w][lane][d];
            ak[d] += part[w][lane][d + 16];
            av[d] += part[w][lane][d + 32];
        }
    }
    __syncthreads();
    if (w == 1) {
#pragma unroll
        for (int d = 0; d < DD; ++d) {
            part[0][lane][d]      = aq[d];
            part[0][lane][d + 16] = ak[d];
            part[0][lane][d + 32] = av[d];
        }
    }
    __syncthreads();
    if (w == 0) {
#pragma unroll
        for (int d = 0; d < DD; ++d) {
            aq[d] += part[0][lane][d];
            ak[d] += part[0][lane][d + 16];
            av[d] += part[0][lane][d + 32];
        }
        float pq0 = xyz_q[((size_t)b * 3 + 0) * NN + n];
        float pq1 = xyz_q[((size_t)b * 3 + 1) * NN + n];
        float pq2 = xyz_q[((size_t)b * 3 + 2) * NN + n];
        float pk0 = xyz_kv[((size_t)b * 3 + 0) * NN + n];
        float pk1 = xyz_kv[((size_t)b * 3 + 1) * NN + n];
        float pk2 = xyz_kv[((size_t)b * 3 + 2) * NN + n];
        size_t base = ((size_t)g0 + lane) * DD;
#pragma unroll
        for (int d = 0; d < DD; ++d) {
            float posq = w_pos_q[d * 3] * pq0 + w_pos_q[d * 3 + 1] * pq1 + w_pos_q[d * 3 + 2] * pq2;
            float posk = w_pos_kv[d * 3] * pk0 + w_pos_kv[d * 3 + 1] * pk1 + w_pos_kv[d * 3 + 2] * pk2;
            q[base + d]  = aq[d] + posq;
            kT[base + d] = ak[d] + posk;
            vT[base + d] = av[d] + b_v[d] + posk;
        }
    }
}

// K2: rowsum partial: thread <-> row, block z-split over m. grid (16,4,32).
__global__ __launch_bounds__(256) void k_rowsum(
    const float* __restrict__ q, const float* __restrict__ kT,
    float* __restrict__ rowsum)
{
    int r = blockIdx.x * 256 + threadIdx.x;
    int b = blockIdx.y;
    int m0 = blockIdx.z * MLEN;
    const float* qp = q + ((size_t)b * NN + r) * DD;
    float qr[DD];
#pragma unroll
    for (int d = 0; d < DD; ++d) qr[d] = qp[d];
    const float* kb = kT + (size_t)b * NN * DD;
    float ps = 0.f;
    for (int m = m0; m < m0 + MLEN; ++m) {
        const float* kv = kb + (size_t)m * DD;     // uniform -> scalar
        float e = 0.f;
#pragma unroll
        for (int d = 0; d < DD; ++d) e = fmaf(kv[d], qr[d], e);
        ps += __expf(e);
    }
    atomicAdd(&rowsum[(size_t)b * NN + r], ps);
}

// K2b: rowinv = 1/rowsum. grid 64 x 256.
__global__ __launch_bounds__(256) void k_rowinv(
    const float* __restrict__ rowsum, float* __restrict__ rowinv)
{
    int i = blockIdx.x * 256 + threadIdx.x;
    rowinv[i] = 1.0f / rowsum[i];
}

// K3: colsum partial: thread <-> column (k in VGPRs), z-split over n. grid (16,4,32).
__global__ __launch_bounds__(256) void k_colsum(
    const float* __restrict__ q, const float* __restrict__ kT,
    const float* __restrict__ rowinv, float* __restrict__ colsum)
{
    int m = blockIdx.x * 256 + threadIdx.x;
    int b = blockIdx.y;
    int n0 = blockIdx.z * MLEN;
    const float* kp = kT + ((size_t)b * NN + m) * DD;
    float kr[DD];
#pragma unroll
    for (int d = 0; d < DD; ++d) kr[d] = kp[d];
    const float* qb = q + (size_t)b * NN * DD;
    const float* ri = rowinv + (size_t)b * NN;
    float cs = 0.f;
    for (int n = n0; n < n0 + MLEN; ++n) {
        const float* qv = qb + (size_t)n * DD;     // uniform -> scalar
        float e = 0.f;
#pragma unroll
        for (int d = 0; d < DD; ++d) e = fmaf(qv[d], kr[d], e);
        cs += __expf(e) * ri[n];
    }
    atomicAdd(&colsum[(size_t)b * NN + m], cs);
}

// K4: vscaled = vT / (1e-9 + colsum). thread <-> element. grid 1024 x 256.
__global__ __launch_bounds__(256) void k_vscale(
    const float* __restrict__ vT, const float* __restrict__ colsum,
    float* __restrict__ vscaled)
{
    int i = blockIdx.x * 256 + threadIdx.x;       // element in [0, B*N*16)
    float cs = colsum[i >> 4];
    vscaled[i] = vT[i] / (1e-9f + cs);
}

// K5: xr[n][d] += rowinv[n] * sum_m exp(q.k) * vscaled[m][d]
// 4 waves: lane <-> row (64 rows/block), wave <-> m-subsplit; LDS combine
// then 16 atomics per row. grid (64,4,8).
__global__ __launch_bounds__(256) void k_xr(
    const float* __restrict__ q, const float* __restrict__ kT,
    const float* __restrict__ vscaled, const float* __restrict__ rowinv,
    float* __restrict__ xr)
{
    __shared__ float part[4][64][17];
    int lane = threadIdx.x & 63;
    int w = threadIdx.x >> 6;
    int r = blockIdx.x * 64 + lane;
    int b = blockIdx.y;
    int m0 = blockIdx.z * 512 + w * 128;

    const float* qp = q + ((size_t)b * NN + r) * DD;
    float qr[DD];
#pragma unroll
    for (int d = 0; d < DD; ++d) qr[d] = qp[d];
    const float* kb = kT + (size_t)b * NN * DD;
    const float* vb = vscaled + (size_t)b * NN * DD;

    float acc[DD];
#pragma unroll
    for (int d = 0; d < DD; ++d) acc[d] = 0.f;

    for (int m = m0; m < m0 + 128; ++m) {
        const float* kv = kb + (size_t)m * DD;     // uniform -> scalar
        const float* vv = vb + (size_t)m * DD;     // uniform -> scalar
        float e = 0.f;
#pragma unroll
        for (int d = 0; d < DD; ++d) e = fmaf(kv[d], qr[d], e);
        float p = __expf(e);
#pragma unroll
        for (int d = 0; d < DD; ++d) acc[d] = fmaf(p, vv[d], acc[d]);
    }
#pragma unroll
    for (int d = 0; d < DD; ++d) part[w][lane][d] = acc[d];
    __syncthreads();
    if (w == 0) {
        float ri = rowinv[(size_t)b * NN + r];
        size_t base = ((size_t)b * NN + r) * DD;
#pragma unroll
        for (int d = 0; d < DD; ++d) {
            float s = acc[d] + part[1][lane][d] + part[2][lane][d] + part[3][lane][d];
            atomicAdd(&xr[base + d], s * ri);
        }
    }
}

// K6: t = w_t*(q - xr) + b_t, plus per-(b,group) sum/sumsq via block reduce.
// grid 64 x 256 (block covers 256 rows of one b).
__global__ __launch_bounds__(256) void k_t_gn(
    const float* __restrict__ q, const float* __restrict__ xr,
    const float* __restrict__ w_t, const float* __restrict__ b_t,
    float* __restrict__ t, float* __restrict__ gnacc)
{
    __shared__ float red[256][9];
    int tid = threadIdx.x;
    int idx = blockIdx.x * 256 + tid;              // b*NN + n
    int b = idx >> 12;
    const float* qp = q  + (size_t)idx * DD;
    const float* xp = xr + (size_t)idx * DD;
    float diff[DD];
#pragma unroll
    for (int d = 0; d < DD; ++d) diff[d] = qp[d] - xp[d];
    float tv[DD];
#pragma unroll
    for (int o = 0; o < DD; ++o) {
        float s = b_t[o];
#pragma unroll
        for (int d = 0; d < DD; ++d) s = fmaf(w_t[o * DD + d], diff[d], s);
        tv[o] = s;
        t[(size_t)idx * DD + o] = s;
    }
#pragma unroll
    for (int g = 0; g < GG; ++g) {
        float s = tv[4*g] + tv[4*g+1] + tv[4*g+2] + tv[4*g+3];
        float sq = tv[4*g]*tv[4*g] + tv[4*g+1]*tv[4*g+1] + tv[4*g+2]*tv[4*g+2] + tv[4*g+3]*tv[4*g+3];
        red[tid][2*g]   = s;
        red[tid][2*g+1] = sq;
    }
    __syncthreads();
    for (int st = 128; st > 0; st >>= 1) {
        if (tid < st) {
#pragma unroll
            for (int j = 0; j < 8; ++j) red[tid][j] += red[tid + st][j];
        }
        __syncthreads();
    }
    if (tid < 8) {
        int g = tid >> 1;
        atomicAdd(&gnacc[(b * GG + g) * 2 + (tid & 1)], red[0][tid]);
    }
}

// K7: out = q + relu(gn(t)). grid 64 x 256.
__global__ __launch_bounds__(256) void k_out(
    const float* __restrict__ q, const float* __restrict__ t,
    const float* __restrict__ gnacc, const float* __restrict__ gamma,
    const float* __restrict__ beta, float* __restrict__ out)
{
    int idx = blockIdx.x * 256 + threadIdx.x;      // b*NN + n
    int b = idx >> 12;
    int n = idx & (NN - 1);
    const float* qv = q + (size_t)idx * DD;
    const float* tv = t + (size_t)idx * DD;
    const float cnt = 1.0f / (4.0f * NN);
#pragma unroll
    for (int o = 0; o < DD; ++o) {
        int g = o >> 2;
        float ms = gnacc[(b * GG + g) * 2 + 0];
        float sq = gnacc[(b * GG + g) * 2 + 1];
        float mean = ms * cnt;
        float var = sq * cnt - mean * mean;
        float rsig = rsqrtf(var + EPSGN);
        float rv = (tv[o] - mean) * rsig * gamma[o] + beta[o];
        rv = fmaxf(rv, 0.f);
        out[((size_t)(b * DD + o)) * NN + n] = qv[o] + rv;
    }
}

extern "C" void kernel_launch(void* const* d_in, const int* in_sizes, int n_in,
                              void* d_out, int out_size, void* d_ws, size_t ws_size,
                              hipStream_t stream)
{
    const float* x_q      = (const float*)d_in[0];
    const float* x_kv     = (const float*)d_in[1];
    const float* xyz_q    = (const float*)d_in[2];
    const float* xyz_kv   = (const float*)d_in[3];
    const float* w_qk     = (const float*)d_in[4];
    const float* w_v      = (const float*)d_in[5];
    const float* b_v      = (const float*)d_in[6];
    const float* w_t      = (const float*)d_in[7];
    const float* b_t      = (const float*)d_in[8];
    const float* gamma    = (const float*)d_in[9];
    const float* beta     = (const float*)d_in[10];
    const float* w_pos_q  = (const float*)d_in[11];
    const float* w_pos_kv = (const float*)d_in[12];

    float* ws = (float*)d_ws;
    float* q       = ws + OFF_Q;
    float* kT      = ws + OFF_KT;
    float* vT      = ws + OFF_VT;
    float* vscaled = ws + OFF_VS;
    float* t       = ws + OFF_T;
    float* rowinv  = ws + OFF_RINV;
    float* rowsum  = ws + OFF_RSUM;
    float* colsum  = ws + OFF_CSUM;
    float* xr      = ws + OFF_XR;
    float* gnacc   = ws + OFF_GN;
    float* out     = (float*)d_out;

    hipMemsetAsync(ws + ZERO_START, 0, (size_t)ZERO_FLTS * 4, stream);

    k_qkv<<<dim3(NB * NN / 64), 256, 0, stream>>>(
        x_q, x_kv, xyz_q, xyz_kv, w_qk, w_v, b_v, w_pos_q, w_pos_kv, q, kT, vT);

    k_rowsum<<<dim3(16, NB, SPLIT), 256, 0, stream>>>(q, kT, rowsum);
    k_rowinv<<<dim3(64), 256, 0, stream>>>(rowsum, rowinv);
    k_colsum<<<dim3(16, NB, SPLIT), 256, 0, stream>>>(q, kT, rowinv, colsum);
    k_vscale<<<dim3(1024), 256, 0, stream>>>(vT, colsum, vscaled);
    k_xr<<<dim3(64, NB, 8), 256, 0, stream>>>(q, kT, vscaled, rowinv, xr);
    k_t_gn<<<dim3(64), 256, 0, stream>>>(q, xr, w_t, b_t, t, gnacc);
    k_out<<<dim3(64), 256, 0, stream>>>(q, t, gnacc, gamma, beta, out);
}

// Round 3
// 382.916 us; speedup vs baseline: 1.4464x; 1.4464x over previous
//
#include <hip/hip_runtime.h>
#include <hip/hip_bf16.h>

#define NB 4
#define CIN 128
#define NN 4096
#define DD 16
#define GG 4
#define EPSGN 1e-5f
#define SPLIT 32
#define MLEN (NN / SPLIT)     // 128 per split task

// ---------------- workspace layout (floats) ----------------
#define OFF_Q      0          // [b][n][d]   262144
#define OFF_KT     262144     // [b][m][d]
#define OFF_VT     524288     // [b][m][d]
#define OFF_VS     786432     // [b][m][d]  v * colinv
#define OFF_T      1048576    // [b][n][o]
#define OFF_RINV   1310720    // [b][n]     16384
#define OFF_RSUM   1327104    // zeroed region starts here
#define OFF_CSUM   1343488
#define OFF_XR     1359872    // [b][n][d]  262144
#define OFF_GN     1622016    // [b][g][2]  32
#define ZERO_START 1327104
#define ZERO_FLTS  294944     // 1622048 - 1327104

static __device__ __forceinline__ int waveid() {
    return __builtin_amdgcn_readfirstlane((int)(threadIdx.x >> 6));
}

// K1: 1x1 convs + positional terms -> q, kT, vT.
// 256 threads = 4 waves; lane <-> n (64 per block), wave <-> 32-channel slice
// (wave index via readfirstlane so w_qk/w_v loads stay SCALAR).
__global__ __launch_bounds__(256) void k_qkv(
    const float* __restrict__ x_q, const float* __restrict__ x_kv,
    const float* __restrict__ xyz_q, const float* __restrict__ xyz_kv,
    const float* __restrict__ w_qk, const float* __restrict__ w_v,
    const float* __restrict__ b_v, const float* __restrict__ w_pos_q,
    const float* __restrict__ w_pos_kv,
    float* __restrict__ q, float* __restrict__ kT, float* __restrict__ vT)
{
    __shared__ float part[2][64][49];
    int lane = threadIdx.x & 63;
    int w = waveid();                  // 0..3, wave-uniform SGPR
    int g0 = blockIdx.x * 64;          // global row base (b*NN+n)
    int b = g0 >> 12;
    int n = (g0 & (NN - 1)) + lane;
    const float* xq = x_q  + (size_t)b * CIN * NN + n;
    const float* xk = x_kv + (size_t)b * CIN * NN + n;

    float aq[DD], ak[DD], av[DD];
#pragma unroll
    for (int d = 0; d < DD; ++d) { aq[d] = 0.f; ak[d] = 0.f; av[d] = 0.f; }

    for (int ci = 0; ci < 32; ++ci) {
        int c = w * 32 + ci;
        float vq = xq[(size_t)c * NN];
        float vk = xk[(size_t)c * NN];
#pragma unroll
        for (int d = 0; d < DD; ++d) {
            float wq = w_qk[d * CIN + c];            // uniform -> scalar
            aq[d] = fmaf(wq, vq, aq[d]);
            ak[d] = fmaf(wq, vk, ak[d]);
            av[d] = fmaf(w_v[d * CIN + c], vk, av[d]);
        }
    }

    // tree combine: waves 2,3 -> LDS; 0,1 add; 1 -> LDS; 0 adds.
    if (w >= 2) {
#pragma unroll
        for (int d = 0; d < DD; ++d) {
            part[w - 2][lane][d]      = aq[d];
            part[w - 2][lane][d + 16] = ak[d];
            part[w - 2][lane][d + 32] = av[d];
        }
    }
    __syncthreads();
    if (w < 2) {
#pragma unroll
        for (int d = 0; d < DD; ++d) {
            aq[d] += part[w][lane][d];
            ak[d] += part[w][lane][d + 16];
            av[d] += part[w][lane][d + 32];
        }
    }
    __syncthreads();
    if (w == 1) {
#pragma unroll
        for (int d = 0; d < DD; ++d) {
            part[0][lane][d]      = aq[d];
            part[0][lane][d + 16] = ak[d];
            part[0][lane][d + 32] = av[d];
        }
    }
    __syncthreads();
    if (w == 0) {
#pragma unroll
        for (int d = 0; d < DD; ++d) {
            aq[d] += part[0][lane][d];
            ak[d] += part[0][lane][d + 16];
            av[d] += part[0][lane][d + 32];
        }
        float pq0 = xyz_q[((size_t)b * 3 + 0) * NN + n];
        float pq1 = xyz_q[((size_t)b * 3 + 1) * NN + n];
        float pq2 = xyz_q[((size_t)b * 3 + 2) * NN + n];
        float pk0 = xyz_kv[((size_t)b * 3 + 0) * NN + n];
        float pk1 = xyz_kv[((size_t)b * 3 + 1) * NN + n];
        float pk2 = xyz_kv[((size_t)b * 3 + 2) * NN + n];
        size_t base = ((size_t)g0 + lane) * DD;
#pragma unroll
        for (int d = 0; d < DD; ++d) {
            float posq = w_pos_q[d * 3] * pq0 + w_pos_q[d * 3 + 1] * pq1 + w_pos_q[d * 3 + 2] * pq2;
            float posk = w_pos_kv[d * 3] * pk0 + w_pos_kv[d * 3 + 1] * pk1 + w_pos_kv[d * 3 + 2] * pk2;
            q[base + d]  = aq[d] + posq;
            kT[base + d] = ak[d] + posk;
            vT[base + d] = av[d] + b_v[d] + posk;
        }
    }
}

// K2: rowsum partial: thread <-> row, block z-split over m. grid (16,4,32).
__global__ __launch_bounds__(256) void k_rowsum(
    const float* __restrict__ q, const float* __restrict__ kT,
    float* __restrict__ rowsum)
{
    int r = blockIdx.x * 256 + threadIdx.x;
    int b = blockIdx.y;
    int m0 = blockIdx.z * MLEN;
    const float* qp = q + ((size_t)b * NN + r) * DD;
    float qr[DD];
#pragma unroll
    for (int d = 0; d < DD; ++d) qr[d] = qp[d];
    const float* kb = kT + (size_t)b * NN * DD;
    float ps = 0.f;
    for (int m = m0; m < m0 + MLEN; ++m) {
        const float* kv = kb + (size_t)m * DD;     // uniform -> scalar
        float e = 0.f;
#pragma unroll
        for (int d = 0; d < DD; ++d) e = fmaf(kv[d], qr[d], e);
        ps += __expf(e);
    }
    atomicAdd(&rowsum[(size_t)b * NN + r], ps);
}

// K2b: rowinv = 1/rowsum. grid 64 x 256.
__global__ __launch_bounds__(256) void k_rowinv(
    const float* __restrict__ rowsum, float* __restrict__ rowinv)
{
    int i = blockIdx.x * 256 + threadIdx.x;
    rowinv[i] = 1.0f / rowsum[i];
}

// K3: colsum partial: thread <-> column (k in VGPRs), z-split over n. grid (16,4,32).
__global__ __launch_bounds__(256) void k_colsum(
    const float* __restrict__ q, const float* __restrict__ kT,
    const float* __restrict__ rowinv, float* __restrict__ colsum)
{
    int m = blockIdx.x * 256 + threadIdx.x;
    int b = blockIdx.y;
    int n0 = blockIdx.z * MLEN;
    const float* kp = kT + ((size_t)b * NN + m) * DD;
    float kr[DD];
#pragma unroll
    for (int d = 0; d < DD; ++d) kr[d] = kp[d];
    const float* qb = q + (size_t)b * NN * DD;
    const float* ri = rowinv + (size_t)b * NN;
    float cs = 0.f;
    for (int n = n0; n < n0 + MLEN; ++n) {
        const float* qv = qb + (size_t)n * DD;     // uniform -> scalar
        float e = 0.f;
#pragma unroll
        for (int d = 0; d < DD; ++d) e = fmaf(qv[d], kr[d], e);
        cs += __expf(e) * ri[n];
    }
    atomicAdd(&colsum[(size_t)b * NN + m], cs);
}

// K4: vscaled = vT / (1e-9 + colsum). thread <-> element. grid 1024 x 256.
__global__ __launch_bounds__(256) void k_vscale(
    const float* __restrict__ vT, const float* __restrict__ colsum,
    float* __restrict__ vscaled)
{
    int i = blockIdx.x * 256 + threadIdx.x;       // element in [0, B*N*16)
    float cs = colsum[i >> 4];
    vscaled[i] = vT[i] / (1e-9f + cs);
}

// K5: xr[n][d] += rowinv[n] * sum_m exp(q.k) * vscaled[m][d]
// 4 waves: lane <-> row (64 rows/block), wave <-> m-subsplit (uniform via
// readfirstlane -> k/v rows are SCALAR loads); LDS combine; 16 atomics/row.
// grid (64,4,8).
__global__ __launch_bounds__(256) void k_xr(
    const float* __restrict__ q, const float* __restrict__ kT,
    const float* __restrict__ vscaled, const float* __restrict__ rowinv,
    float* __restrict__ xr)
{
    __shared__ float part[4][64][17];
    int lane = threadIdx.x & 63;
    int w = waveid();                              // wave-uniform SGPR
    int r = blockIdx.x * 64 + lane;
    int b = blockIdx.y;
    int m0 = blockIdx.z * 512 + w * 128;

    const float* qp = q + ((size_t)b * NN + r) * DD;
    float qr[DD];
#pragma unroll
    for (int d = 0; d < DD; ++d) qr[d] = qp[d];
    const float* kb = kT + (size_t)b * NN * DD;
    const float* vb = vscaled + (size_t)b * NN * DD;

    float acc[DD];
#pragma unroll
    for (int d = 0; d < DD; ++d) acc[d] = 0.f;

    for (int m = m0; m < m0 + 128; ++m) {
        const float* kv = kb + (size_t)m * DD;     // uniform -> scalar
        const float* vv = vb + (size_t)m * DD;     // uniform -> scalar
        float e = 0.f;
#pragma unroll
        for (int d = 0; d < DD; ++d) e = fmaf(kv[d], qr[d], e);
        float p = __expf(e);
#pragma unroll
        for (int d = 0; d < DD; ++d) acc[d] = fmaf(p, vv[d], acc[d]);
    }
#pragma unroll
    for (int d = 0; d < DD; ++d) part[w][lane][d] = acc[d];
    __syncthreads();
    if (w == 0) {
        float ri = rowinv[(size_t)b * NN + r];
        size_t base = ((size_t)b * NN + r) * DD;
#pragma unroll
        for (int d = 0; d < DD; ++d) {
            float s = acc[d] + part[1][lane][d] + part[2][lane][d] + part[3][lane][d];
            atomicAdd(&xr[base + d], s * ri);
        }
    }
}

// K6: t = w_t*(q - xr) + b_t, plus per-(b,group) sum/sumsq via block reduce.
// grid 64 x 256 (block covers 256 rows of one b).
__global__ __launch_bounds__(256) void k_t_gn(
    const float* __restrict__ q, const float* __restrict__ xr,
    const float* __restrict__ w_t, const float* __restrict__ b_t,
    float* __restrict__ t, float* __restrict__ gnacc)
{
    __shared__ float red[256][9];
    int tid = threadIdx.x;
    int idx = blockIdx.x * 256 + tid;              // b*NN + n
    int b = idx >> 12;
    const float* qp = q  + (size_t)idx * DD;
    const float* xp = xr + (size_t)idx * DD;
    float diff[DD];
#pragma unroll
    for (int d = 0; d < DD; ++d) diff[d] = qp[d] - xp[d];
    float tv[DD];
#pragma unroll
    for (int o = 0; o < DD; ++o) {
        float s = b_t[o];
#pragma unroll
        for (int d = 0; d < DD; ++d) s = fmaf(w_t[o * DD + d], diff[d], s);
        tv[o] = s;
        t[(size_t)idx * DD + o] = s;
    }
#pragma unroll
    for (int g = 0; g < GG; ++g) {
        float s = tv[4*g] + tv[4*g+1] + tv[4*g+2] + tv[4*g+3];
        float sq = tv[4*g]*tv[4*g] + tv[4*g+1]*tv[4*g+1] + tv[4*g+2]*tv[4*g+2] + tv[4*g+3]*tv[4*g+3];
        red[tid][2*g]   = s;
        red[tid][2*g+1] = sq;
    }
    __syncthreads();
    for (int st = 128; st > 0; st >>= 1) {
        if (tid < st) {
#pragma unroll
            for (int j = 0; j < 8; ++j) red[tid][j] += red[tid + st][j];
        }
        __syncthreads();
    }
    if (tid < 8) {
        int g = tid >> 1;
        atomicAdd(&gnacc[(b * GG + g) * 2 + (tid & 1)], red[0][tid]);
    }
}

// K7: out = q + relu(gn(t)). grid 64 x 256.
__global__ __launch_bounds__(256) void k_out(
    const float* __restrict__ q, const float* __restrict__ t,
    const float* __restrict__ gnacc, const float* __restrict__ gamma,
    const float* __restrict__ beta, float* __restrict__ out)
{
    int idx = blockIdx.x * 256 + threadIdx.x;      // b*NN + n
    int b = idx >> 12;
    int n = idx & (NN - 1);
    const float* qv = q + (size_t)idx * DD;
    const float* tv = t + (size_t)idx * DD;
    const float cnt = 1.0f / (4.0f * NN);
#pragma unroll
    for (int o = 0; o < DD; ++o) {
        int g = o >> 2;
        float ms = gnacc[(b * GG + g) * 2 + 0];
        float sq = gnacc[(b * GG + g) * 2 + 1];
        float mean = ms * cnt;
        float var = sq * cnt - mean * mean;
        float rsig = rsqrtf(var + EPSGN);
        float rv = (tv[o] - mean) * rsig * gamma[o] + beta[o];
        rv = fmaxf(rv, 0.f);
        out[((size_t)(b * DD + o)) * NN + n] = qv[o] + rv;
    }
}

extern "C" void kernel_launch(void* const* d_in, const int* in_sizes, int n_in,
                              void* d_out, int out_size, void* d_ws, size_t ws_size,
                              hipStream_t stream)
{
    const float* x_q      = (const float*)d_in[0];
    const float* x_kv     = (const float*)d_in[1];
    const float* xyz_q    = (const float*)d_in[2];
    const float* xyz_kv   = (const float*)d_in[3];
    const float* w_qk     = (const float*)d_in[4];
    const float* w_v      = (const float*)d_in[5];
    const float* b_v      = (const float*)d_in[6];
    const float* w_t      = (const float*)d_in[7];
    const float* b_t      = (const float*)d_in[8];
    const float* gamma    = (const float*)d_in[9];
    const float* beta     = (const float*)d_in[10];
    const float* w_pos_q  = (const float*)d_in[11];
    const float* w_pos_kv = (const float*)d_in[12];

    float* ws = (float*)d_ws;
    float* q       = ws + OFF_Q;
    float* kT      = ws + OFF_KT;
    float* vT      = ws + OFF_VT;
    float* vscaled = ws + OFF_VS;
    float* t       = ws + OFF_T;
    float* rowinv  = ws + OFF_RINV;
    float* rowsum  = ws + OFF_RSUM;
    float* colsum  = ws + OFF_CSUM;
    float* xr      = ws + OFF_XR;
    float* gnacc   = ws + OFF_GN;
    float* out     = (float*)d_out;

    hipMemsetAsync(ws + ZERO_START, 0, (size_t)ZERO_FLTS * 4, stream);

    k_qkv<<<dim3(NB * NN / 64), 256, 0, stream>>>(
        x_q, x_kv, xyz_q, xyz_kv, w_qk, w_v, b_v, w_pos_q, w_pos_kv, q, kT, vT);

    k_rowsum<<<dim3(16, NB, SPLIT), 256, 0, stream>>>(q, kT, rowsum);
    k_rowinv<<<dim3(64), 256, 0, stream>>>(rowsum, rowinv);
    k_colsum<<<dim3(16, NB, SPLIT), 256, 0, stream>>>(q, kT, rowinv, colsum);
    k_vscale<<<dim3(1024), 256, 0, stream>>>(vT, colsum, vscaled);
    k_xr<<<dim3(64, NB, 8), 256, 0, stream>>>(q, kT, vscaled, rowinv, xr);
    k_t_gn<<<dim3(64), 256, 0, stream>>>(q, xr, w_t, b_t, t, gnacc);
    k_out<<<dim3(64), 256, 0, stream>>>(q, t, gnacc, gamma, beta, out);
}

// Round 4
// 190.496 us; speedup vs baseline: 2.9074x; 2.0101x over previous
//
#include <hip/hip_runtime.h>
#include <hip/hip_bf16.h>

#define NB 4
#define CIN 128
#define NN 4096
#define DD 16
#define GG 4
#define EPSGN 1e-5f

typedef __attribute__((ext_vector_type(8))) short short8_t;
typedef __attribute__((ext_vector_type(4))) float f32x4;

// ---------------- workspace layout (float slots) ----------------
#define OFF_Q      0          // q f32 [b][n][16]              262144
#define OFF_VT     262144     // vT f32 [b][m][16]; ALIASED as xr after k_vsb
#define OFF_RINV   524288     // f32 [b][n]  16384
#define OFF_CINV   540672     // f32 [b][m]  16384
#define OFF_GN     557056     // f32 [b][g][2]  32 (pad to 557088)
#define OFF_QB     557088     // bf16 [b][n][32] (d>=16 zero) = 524288 ushort = 262144 slots; ALIASED as t f32 after k_xr
#define OFF_KB     819232     // bf16 [b][m][32] (d>=16 zero)
#define OFF_VSB    1081376    // bf16 [b][d][4096]  = 262144 ushort = 131072 slots
// total 1212448 floats = 4.85 MB

static __device__ __forceinline__ int waveid() {
    return __builtin_amdgcn_readfirstlane((int)(threadIdx.x >> 6));
}
static __device__ __forceinline__ unsigned short f2bf(float x) {
    unsigned int u = __float_as_uint(x);
    u = (u + 0x7FFFu + ((u >> 16) & 1u)) >> 16;
    return (unsigned short)u;
}
static __device__ __forceinline__ unsigned int packbf(float a, float b) {
    return (unsigned int)f2bf(a) | ((unsigned int)f2bf(b) << 16);
}

// K1: 1x1 convs + positional terms -> q (f32), qb/kb (bf16, 32-padded), vT (f32).
// 4 waves, lane <-> row (64/block), wave <-> 32-channel slice, LDS tree combine.
__global__ __launch_bounds__(256) void k_qkv(
    const float* __restrict__ x_q, const float* __restrict__ x_kv,
    const float* __restrict__ xyz_q, const float* __restrict__ xyz_kv,
    const float* __restrict__ w_qk, const float* __restrict__ w_v,
    const float* __restrict__ b_v, const float* __restrict__ w_pos_q,
    const float* __restrict__ w_pos_kv,
    float* __restrict__ q, unsigned short* __restrict__ qb,
    unsigned short* __restrict__ kb, float* __restrict__ vT)
{
    __shared__ float part[2][64][49];
    int lane = threadIdx.x & 63;
    int w = waveid();
    int g0 = blockIdx.x * 64;          // b*NN + n base
    int b = g0 >> 12;
    int n = (g0 & (NN - 1)) + lane;
    const float* xq = x_q  + (size_t)b * CIN * NN + n;
    const float* xk = x_kv + (size_t)b * CIN * NN + n;

    float aq[DD], ak[DD], av[DD];
#pragma unroll
    for (int d = 0; d < DD; ++d) { aq[d] = 0.f; ak[d] = 0.f; av[d] = 0.f; }

    for (int ci = 0; ci < 32; ++ci) {
        int c = w * 32 + ci;
        float vq = xq[(size_t)c * NN];
        float vk = xk[(size_t)c * NN];
#pragma unroll
        for (int d = 0; d < DD; ++d) {
            float wq = w_qk[d * CIN + c];            // uniform -> scalar
            aq[d] = fmaf(wq, vq, aq[d]);
            ak[d] = fmaf(wq, vk, ak[d]);
            av[d] = fmaf(w_v[d * CIN + c], vk, av[d]);
        }
    }

    if (w >= 2) {
#pragma unroll
        for (int d = 0; d < DD; ++d) {
            part[w - 2][lane][d]      = aq[d];
            part[w - 2][lane][d + 16] = ak[d];
            part[w - 2][lane][d + 32] = av[d];
        }
    }
    __syncthreads();
    if (w < 2) {
#pragma unroll
        for (int d = 0; d < DD; ++d) {
            aq[d] += part[w][lane][d];
            ak[d] += part[w][lane][d + 16];
            av[d] += part[w][lane][d + 32];
        }
    }
    __syncthreads();
    if (w == 1) {
#pragma unroll
        for (int d = 0; d < DD; ++d) {
            part[0][lane][d]      = aq[d];
            part[0][lane][d + 16] = ak[d];
            part[0][lane][d + 32] = av[d];
        }
    }
    __syncthreads();
    if (w == 0) {
#pragma unroll
        for (int d = 0; d < DD; ++d) {
            aq[d] += part[0][lane][d];
            ak[d] += part[0][lane][d + 16];
            av[d] += part[0][lane][d + 32];
        }
        float pq0 = xyz_q[((size_t)b * 3 + 0) * NN + n];
        float pq1 = xyz_q[((size_t)b * 3 + 1) * NN + n];
        float pq2 = xyz_q[((size_t)b * 3 + 2) * NN + n];
        float pk0 = xyz_kv[((size_t)b * 3 + 0) * NN + n];
        float pk1 = xyz_kv[((size_t)b * 3 + 1) * NN + n];
        float pk2 = xyz_kv[((size_t)b * 3 + 2) * NN + n];
        size_t row = (size_t)g0 + lane;
        float qv[DD], kv[DD];
#pragma unroll
        for (int d = 0; d < DD; ++d) {
            float posq = w_pos_q[d * 3] * pq0 + w_pos_q[d * 3 + 1] * pq1 + w_pos_q[d * 3 + 2] * pq2;
            float posk = w_pos_kv[d * 3] * pk0 + w_pos_kv[d * 3 + 1] * pk1 + w_pos_kv[d * 3 + 2] * pk2;
            qv[d] = aq[d] + posq;
            kv[d] = ak[d] + posk;
            q[row * DD + d]  = qv[d];
            vT[row * DD + d] = av[d] + b_v[d] + posk;
        }
        unsigned int* qbw = (unsigned int*)(qb + row * 32);
        unsigned int* kbw = (unsigned int*)(kb + row * 32);
#pragma unroll
        for (int h = 0; h < 8; ++h) {
            qbw[h] = packbf(qv[2 * h], qv[2 * h + 1]);
            kbw[h] = packbf(kv[2 * h], kv[2 * h + 1]);
            qbw[h + 8] = 0u;                 // zero-pad d=16..31
            kbw[h + 8] = 0u;
        }
    }
}

// K2: rowinv via swapped MFMA: D[m,n] = K-tile x Q-tile^T; n lane-local.
// grid (NN/16, NB), block 256 (4 waves m-interleaved).
__global__ __launch_bounds__(256) void k_rows(
    const unsigned short* __restrict__ qb, const unsigned short* __restrict__ kb,
    float* __restrict__ rowinv)
{
    __shared__ float red[4][16];
    int lane = threadIdx.x & 63;
    int w = waveid();
    int j = lane & 15, g = lane >> 4;
    int b = blockIdx.y;
    int n0 = blockIdx.x * 16;

    short8_t qf = *reinterpret_cast<const short8_t*>(qb + ((size_t)(b * NN + n0 + j)) * 32 + 8 * g);
    const unsigned short* kbb = kb + (size_t)b * NN * 32;

    float rs = 0.f;
#pragma unroll 2
    for (int mt = w; mt < 256; mt += 4) {
        short8_t kf = *reinterpret_cast<const short8_t*>(kbb + ((size_t)(mt * 16 + j)) * 32 + 8 * g);
        f32x4 c = __builtin_amdgcn_mfma_f32_16x16x32_bf16(kf, qf, (f32x4){0.f, 0.f, 0.f, 0.f}, 0, 0, 0);
        rs += __expf(c[0]) + __expf(c[1]) + __expf(c[2]) + __expf(c[3]);
    }
    rs += __shfl_xor(rs, 16);
    rs += __shfl_xor(rs, 32);
    if (lane < 16) red[w][lane] = rs;
    __syncthreads();
    if (threadIdx.x < 16)
        rowinv[(size_t)b * NN + n0 + threadIdx.x] =
            1.0f / (red[0][threadIdx.x] + red[1][threadIdx.x] + red[2][threadIdx.x] + red[3][threadIdx.x]);
}

// K3: colinv via non-swapped MFMA: D[n,m] = Q-tile x K-tile^T; m lane-local.
// rinv staged in LDS. grid (NN/16, NB), block 256.
__global__ __launch_bounds__(256) void k_cols(
    const unsigned short* __restrict__ qb, const unsigned short* __restrict__ kb,
    const float* __restrict__ rowinv, float* __restrict__ colinv)
{
    __shared__ float ri_l[NN];
    __shared__ float red[4][16];
    int lane = threadIdx.x & 63;
    int w = waveid();
    int j = lane & 15, g = lane >> 4;
    int b = blockIdx.y;
    int m0 = blockIdx.x * 16;

    {   // coalesced stage of rowinv[b][:]
        const float4* src = (const float4*)(rowinv + (size_t)b * NN);
        float4* dst = (float4*)ri_l;
        for (int i = threadIdx.x; i < NN / 4; i += 256) dst[i] = src[i];
    }
    short8_t kf = *reinterpret_cast<const short8_t*>(kb + ((size_t)(b * NN + m0 + j)) * 32 + 8 * g);
    const unsigned short* qbb = qb + (size_t)b * NN * 32;
    __syncthreads();

    float cs = 0.f;
#pragma unroll 2
    for (int nt = w; nt < 256; nt += 4) {
        short8_t qf = *reinterpret_cast<const short8_t*>(qbb + ((size_t)(nt * 16 + j)) * 32 + 8 * g);
        f32x4 c = __builtin_amdgcn_mfma_f32_16x16x32_bf16(qf, kf, (f32x4){0.f, 0.f, 0.f, 0.f}, 0, 0, 0);
        const float4 rv = *reinterpret_cast<const float4*>(&ri_l[nt * 16 + 4 * g]);
        cs += __expf(c[0]) * rv.x + __expf(c[1]) * rv.y + __expf(c[2]) * rv.z + __expf(c[3]) * rv.w;
    }
    cs += __shfl_xor(cs, 16);
    cs += __shfl_xor(cs, 32);
    if (lane < 16) red[w][lane] = cs;
    __syncthreads();
    if (threadIdx.x < 16)
        colinv[(size_t)b * NN + m0 + threadIdx.x] =
            1.0f / (1e-9f + red[0][threadIdx.x] + red[1][threadIdx.x] + red[2][threadIdx.x] + red[3][threadIdx.x]);
}

// K4: vsbT[b][d][m] = bf16(vT[b][m][d] * colinv[b][m]).  grid (16, NB), 256 thr.
__global__ __launch_bounds__(256) void k_vsb(
    const float* __restrict__ vT, const float* __restrict__ colinv,
    unsigned short* __restrict__ vsb)
{
    __shared__ float vl[256 * 17];
    int t = threadIdx.x;
    int b = blockIdx.y;
    int m0 = blockIdx.x * 256;
    const float4* src = (const float4*)(vT + ((size_t)b * NN + m0) * DD);
#pragma unroll
    for (int i = 0; i < 4; ++i) {
        float4 v = src[i * 256 + t];
        int flat = (i * 256 + t) * 4;
        int r = flat >> 4, c = flat & 15;
        vl[r * 17 + c]     = v.x;
        vl[r * 17 + c + 1] = v.y;
        vl[r * 17 + c + 2] = v.z;
        vl[r * 17 + c + 3] = v.w;
    }
    __syncthreads();
    float ci = colinv[(size_t)b * NN + m0 + t];
#pragma unroll
    for (int d = 0; d < DD; ++d)
        vsb[((size_t)(b * DD + d)) * NN + m0 + t] = f2bf(vl[t * 17 + d] * ci);
}

// K5: xr via double-MFMA: per 32-m chunk, two swapped QK tiles -> exp*rinv ->
// bf16 P^T (C-layout == PV B-frag after per-wave LDS repack) -> PV mfma
// accumulates xr^T[d][n].  grid (NN/16, NB), block 256 (4 waves, m-split).
__global__ __launch_bounds__(256) void k_xr(
    const unsigned short* __restrict__ qb, const unsigned short* __restrict__ kb,
    const unsigned short* __restrict__ vsb, const float* __restrict__ rowinv,
    float* __restrict__ xr)
{
    __shared__ __align__(16) unsigned int plds_all[4][320];   // per-wave [16 n][pitch 20 uints = 40 bf16]
    __shared__ float xls[4][64][4];
    int lane = threadIdx.x & 63;
    int w = waveid();
    int j = lane & 15, g = lane >> 4;
    int b = blockIdx.y;
    int n0 = blockIdx.x * 16;
    unsigned int* plds = plds_all[w];

    short8_t qf = *reinterpret_cast<const short8_t*>(qb + ((size_t)(b * NN + n0 + j)) * 32 + 8 * g);
    float ri = rowinv[(size_t)b * NN + n0 + j];
    const unsigned short* kbb = kb + (size_t)b * NN * 32;
    const unsigned short* vsbb = vsb + (size_t)b * DD * NN;

    f32x4 acc = {0.f, 0.f, 0.f, 0.f};
    for (int MC = w; MC < 128; MC += 4) {       // 32-wide m chunk
        int M = MC * 32;
        short8_t kf0 = *reinterpret_cast<const short8_t*>(kbb + ((size_t)(M + j)) * 32 + 8 * g);
        short8_t kf1 = *reinterpret_cast<const short8_t*>(kbb + ((size_t)(M + 16 + j)) * 32 + 8 * g);
        f32x4 c0 = __builtin_amdgcn_mfma_f32_16x16x32_bf16(kf0, qf, (f32x4){0.f, 0.f, 0.f, 0.f}, 0, 0, 0);
        f32x4 c1 = __builtin_amdgcn_mfma_f32_16x16x32_bf16(kf1, qf, (f32x4){0.f, 0.f, 0.f, 0.f}, 0, 0, 0);
        // P = exp(e) * rinv[n]; lane holds rows m = 4g+r (tile0), 16+4g+r (tile1), col n = j
        float p00 = __expf(c0[0]) * ri, p01 = __expf(c0[1]) * ri;
        float p02 = __expf(c0[2]) * ri, p03 = __expf(c0[3]) * ri;
        float p10 = __expf(c1[0]) * ri, p11 = __expf(c1[1]) * ri;
        float p12 = __expf(c1[2]) * ri, p13 = __expf(c1[3]) * ri;
        // repack: P_lds[n=j][m] bf16, pitch 40 bf16 (20 uints)
        int base = j * 20;
        plds[base + 2 * g]     = packbf(p00, p01);   // m = 4g, 4g+1
        plds[base + 2 * g + 1] = packbf(p02, p03);   // m = 4g+2, 4g+3
        plds[base + 8 + 2 * g]     = packbf(p10, p11);   // m = 16+4g..
        plds[base + 8 + 2 * g + 1] = packbf(p12, p13);
        // B-frag read: lane (g,j): n=j, m = 8g..8g+7 -> 16B aligned (80j+16g)
        short8_t pf = *reinterpret_cast<const short8_t*>(&plds[base + 4 * g]);
        // A-frag: vs^T: lane: d = j, m = M + 8g..+7
        short8_t vf = *reinterpret_cast<const short8_t*>(vsbb + ((size_t)j) * NN + M + 8 * g);
        acc = __builtin_amdgcn_mfma_f32_16x16x32_bf16(vf, pf, acc, 0, 0, 0);
    }
#pragma unroll
    for (int r = 0; r < 4; ++r) xls[w][lane][r] = acc[r];
    __syncthreads();
    if (w == 0) {
        float4 tot;
        tot.x = xls[0][lane][0] + xls[1][lane][0] + xls[2][lane][0] + xls[3][lane][0];
        tot.y = xls[0][lane][1] + xls[1][lane][1] + xls[2][lane][1] + xls[3][lane][1];
        tot.z = xls[0][lane][2] + xls[1][lane][2] + xls[2][lane][2] + xls[3][lane][2];
        tot.w = xls[0][lane][3] + xls[1][lane][3] + xls[2][lane][3] + xls[3][lane][3];
        // lane (g,j): xr[b][n0+j][d=4g..4g+3]
        *reinterpret_cast<float4*>(xr + ((size_t)(b * NN + n0 + j)) * DD + 4 * g) = tot;
    }
}

// K6: t = w_t*(q - xr) + b_t, plus per-(b,group) sum/sumsq atomics. grid 64 x 256.
__global__ __launch_bounds__(256) void k_t_gn(
    const float* __restrict__ q, const float* __restrict__ xr,
    const float* __restrict__ w_t, const float* __restrict__ b_t,
    float* __restrict__ t, float* __restrict__ gnacc)
{
    __shared__ float red[256][9];
    int tid = threadIdx.x;
    int idx = blockIdx.x * 256 + tid;              // b*NN + n
    int b = idx >> 12;
    const float* qp = q  + (size_t)idx * DD;
    const float* xp = xr + (size_t)idx * DD;
    float diff[DD];
#pragma unroll
    for (int d = 0; d < DD; ++d) diff[d] = qp[d] - xp[d];
    float tv[DD];
#pragma unroll
    for (int o = 0; o < DD; ++o) {
        float s = b_t[o];
#pragma unroll
        for (int d = 0; d < DD; ++d) s = fmaf(w_t[o * DD + d], diff[d], s);
        tv[o] = s;
        t[(size_t)idx * DD + o] = s;
    }
#pragma unroll
    for (int g = 0; g < GG; ++g) {
        float s = tv[4*g] + tv[4*g+1] + tv[4*g+2] + tv[4*g+3];
        float sq = tv[4*g]*tv[4*g] + tv[4*g+1]*tv[4*g+1] + tv[4*g+2]*tv[4*g+2] + tv[4*g+3]*tv[4*g+3];
        red[tid][2*g]   = s;
        red[tid][2*g+1] = sq;
    }
    __syncthreads();
    for (int st = 128; st > 0; st >>= 1) {
        if (tid < st) {
#pragma unroll
            for (int jj = 0; jj < 8; ++jj) red[tid][jj] += red[tid + st][jj];
        }
        __syncthreads();
    }
    if (tid < 8) {
        int g = tid >> 1;
        atomicAdd(&gnacc[(b * GG + g) * 2 + (tid & 1)], red[0][tid]);
    }
}

// K7: out = q + relu(gn(t)). grid 64 x 256.
__global__ __launch_bounds__(256) void k_out(
    const float* __restrict__ q, const float* __restrict__ t,
    const float* __restrict__ gnacc, const float* __restrict__ gamma,
    const float* __restrict__ beta, float* __restrict__ out)
{
    int idx = blockIdx.x * 256 + threadIdx.x;      // b*NN + n
    int b = idx >> 12;
    int n = idx & (NN - 1);
    const float* qv = q + (size_t)idx * DD;
    const float* tv = t + (size_t)idx * DD;
    const float cnt = 1.0f / (4.0f * NN);
#pragma unroll
    for (int o = 0; o < DD; ++o) {
        int g = o >> 2;
        float ms = gnacc[(b * GG + g) * 2 + 0];
        float sq = gnacc[(b * GG + g) * 2 + 1];
        float mean = ms * cnt;
        float var = sq * cnt - mean * mean;
        float rsig = rsqrtf(var + EPSGN);
        float rv = (tv[o] - mean) * rsig * gamma[o] + beta[o];
        rv = fmaxf(rv, 0.f);
        out[((size_t)(b * DD + o)) * NN + n] = qv[o] + rv;
    }
}

extern "C" void kernel_launch(void* const* d_in, const int* in_sizes, int n_in,
                              void* d_out, int out_size, void* d_ws, size_t ws_size,
                              hipStream_t stream)
{
    const float* x_q      = (const float*)d_in[0];
    const float* x_kv     = (const float*)d_in[1];
    const float* xyz_q    = (const float*)d_in[2];
    const float* xyz_kv   = (const float*)d_in[3];
    const float* w_qk     = (const float*)d_in[4];
    const float* w_v      = (const float*)d_in[5];
    const float* b_v      = (const float*)d_in[6];
    const float* w_t      = (const float*)d_in[7];
    const float* b_t      = (const float*)d_in[8];
    const float* gamma    = (const float*)d_in[9];
    const float* beta     = (const float*)d_in[10];
    const float* w_pos_q  = (const float*)d_in[11];
    const float* w_pos_kv = (const float*)d_in[12];

    float* ws = (float*)d_ws;
    float* q       = ws + OFF_Q;
    float* vT      = ws + OFF_VT;      // aliased: xr after k_vsb consumes vT
    float* xr      = ws + OFF_VT;
    float* rowinv  = ws + OFF_RINV;
    float* colinv  = ws + OFF_CINV;
    float* gnacc   = ws + OFF_GN;
    unsigned short* qb  = (unsigned short*)(ws + OFF_QB);
    float* t       = ws + OFF_QB;      // aliased: t after k_xr consumes qb
    unsigned short* kb  = (unsigned short*)(ws + OFF_KB);
    unsigned short* vsb = (unsigned short*)(ws + OFF_VSB);
    float* out     = (float*)d_out;

    hipMemsetAsync(gnacc, 0, 32 * sizeof(float), stream);

    k_qkv<<<dim3(NB * NN / 64), 256, 0, stream>>>(
        x_q, x_kv, xyz_q, xyz_kv, w_qk, w_v, b_v, w_pos_q, w_pos_kv, q, qb, kb, vT);

    dim3 gt(NN / 16, NB);
    k_rows<<<gt, 256, 0, stream>>>(qb, kb, rowinv);
    k_cols<<<gt, 256, 0, stream>>>(qb, kb, rowinv, colinv);
    k_vsb<<<dim3(NN / 256, NB), 256, 0, stream>>>(vT, colinv, vsb);
    k_xr<<<gt, 256, 0, stream>>>(qb, kb, vsb, rowinv, xr);
    k_t_gn<<<dim3(NB * NN / 256), 256, 0, stream>>>(q, xr, w_t, b_t, t, gnacc);
    k_out<<<dim3(NB * NN / 256), 256, 0, stream>>>(q, t, gnacc, gamma, beta, out);
}